// Round 10
// baseline (238.847 us; speedup 1.0000x reference)
//
#include <hip/hip_runtime.h>
#include <hip/hip_bf16.h>
#include <stdint.h>

typedef __attribute__((ext_vector_type(8))) short short8;
typedef __attribute__((ext_vector_type(4))) float floatx4;
typedef __attribute__((ext_vector_type(16))) float floatx16;
typedef __attribute__((ext_vector_type(2))) long longx2;

#define DEVI __device__ __forceinline__
#define MFMA16(a, b, c) __builtin_amdgcn_mfma_f32_16x16x32_bf16((a), (b), (c), 0, 0, 0)
#define MFMA32(a, b, c) __builtin_amdgcn_mfma_f32_32x32x16_fp8_fp8((a), (b), (c), 0, 0, 0)

typedef __attribute__((address_space(3))) unsigned int lds_u32;
typedef __attribute__((address_space(1))) const unsigned int glb_u32;
// async 16B/lane DMA global->LDS: lds dest = wave-uniform base + lane*16 (contiguous 1KB/wave)
#define GLOAD_LDS16(g, l) __builtin_amdgcn_global_load_lds((glb_u32*)(g), (lds_u32*)(l), 16, 0, 0)

DEVI unsigned short f2bf(float x) {
    union { float f; unsigned int u; } v; v.f = x;
    unsigned int r = v.u + 0x7FFFu + ((v.u >> 16) & 1u);
    return (unsigned short)(r >> 16);
}
DEVI float bf2f(unsigned short h) {
    union { unsigned int u; float f; } v; v.u = ((unsigned int)h) << 16;
    return v.f;
}
DEVI unsigned char f2fp8(float x) {   // OCP e4m3 via HW converter
    int c = __builtin_amdgcn_cvt_pk_fp8_f32(x, x, 0, false);
    return (unsigned char)(c & 0xFF);
}

// ---------------- fused weight prep: all 4 transpose+casts in one launch ----------------
// Tp[n][k] = bf16(Wp[k][n]) (128x256 -> 256x128); Tq/Tk/Tv same for 256x256.
__global__ __launch_bounds__(256) void prep_weights(
    const float* __restrict__ Wp, const float* __restrict__ Wq,
    const float* __restrict__ Wk, const float* __restrict__ Wv,
    unsigned short* __restrict__ Tp, unsigned short* __restrict__ Tq,
    unsigned short* __restrict__ Tk, unsigned short* __restrict__ Tv)
{
    int idx = blockIdx.x * blockDim.x + threadIdx.x;   // 0 .. 229375
    if (idx < 32768) {
        int k = idx >> 8, n = idx & 255;
        Tp[n * 128 + k] = f2bf(Wp[idx]);
    } else {
        int r = idx - 32768;
        int m = r >> 16, i = r & 65535;                // m = 0,1,2
        const float* W   = (m == 0) ? Wq : (m == 1) ? Wk : Wv;
        unsigned short* T = (m == 0) ? Tq : (m == 1) ? Tk : Tv;
        int k = i >> 8, n = i & 255;
        T[n * 256 + k] = f2bf(W[i]);
    }
}

// ---------------- projection GEMM: x = f32_in @ Wp^T + bias (fused cast, bf16 out) ----------------

__global__ __launch_bounds__(256) void gemm_bias(
    const float* __restrict__ A,               // f32 input [16384][128]
    const unsigned short* __restrict__ Wt,     // bf16 [256][128]
    const float* __restrict__ bias,
    unsigned short* __restrict__ Cb,           // bf16 out [16384][256]
    int N)
{
    __shared__ __align__(16) unsigned short As[64][136];
    __shared__ __align__(16) unsigned short Bs[64][136];
    const int tid  = threadIdx.x;
    const int w    = tid >> 6;
    const int lane = tid & 63;
    const int quad = lane >> 4;
    const int l15  = lane & 15;
    const int m0 = blockIdx.x * 64;
    const int n0 = blockIdx.y * 64;

    floatx4 acc[4];
    #pragma unroll
    for (int t = 0; t < 4; ++t) acc[t] = (floatx4)0.0f;

    // K = 128: single chunk. A staged f32 -> bf16 in-register (fused cast).
    #pragma unroll
    for (int it = 0; it < 8; ++it) {
        int idx = tid + it * 256;             // 0..2047 float4s
        int r = idx >> 5, c4 = idx & 31;
        float4 v = *(const float4*)&A[(size_t)(m0 + r) * 128 + c4 * 4];
        ushort4 o;
        o.x = f2bf(v.x); o.y = f2bf(v.y); o.z = f2bf(v.z); o.w = f2bf(v.w);
        *(ushort4*)&As[r][c4 * 4] = o;
    }
    #pragma unroll
    for (int it = 0; it < 4; ++it) {
        int idx = tid + it * 256;             // 0..1023 x 8 bf16
        int r = idx >> 4, g = idx & 15;
        *(short8*)&Bs[r][g * 8] = *(const short8*)&Wt[(size_t)(n0 + r) * 128 + g * 8];
    }
    __syncthreads();
    #pragma unroll
    for (int s = 0; s < 4; ++s) {
        short8 a = *(const short8*)&As[w * 16 + l15][s * 32 + quad * 8];
        #pragma unroll
        for (int t = 0; t < 4; ++t) {
            short8 bfr = *(const short8*)&Bs[t * 16 + l15][s * 32 + quad * 8];
            acc[t] = MFMA16(a, bfr, acc[t]);
        }
    }

    // epilogue via LDS overlay -> coalesced 16B stores (BOTH column halves: 512 int4s, 256 thr)
    __syncthreads();
    unsigned short* T = &As[0][0];            // 64 x 80 ushort overlay (10 KB)
    #pragma unroll
    for (int t = 0; t < 4; ++t) {
        int n = n0 + t * 16 + l15;
        float bs = bias[n];
        #pragma unroll
        for (int r = 0; r < 4; ++r)
            T[(w * 16 + quad * 4 + r) * 80 + t * 16 + l15] = f2bf(acc[t][r] + bs);
    }
    __syncthreads();
    int row = tid >> 2, c8 = (tid & 3) * 8;
    #pragma unroll
    for (int half = 0; half < 2; ++half) {
        int4 ov = *(const int4*)&T[row * 80 + c8 + half * 32];
        *(int4*)&Cb[(size_t)(m0 + row) * N + n0 + c8 + half * 32] = ov;
    }
}

// ---------------- fused Q/K/V GEMM with fp8 + fragment-packed output ----------------
// blockIdx.z selects weight/bias/output. Q written row-major fp8; K and V written DIRECTLY
// in the 32x32x16 slice-paired fragment layout flash_attn consumes. All global stores
// 16B/thread via a 5 KB LDS tile-transpose overlaid on As.
//
// Packed layouts (per batch, 1 MB, tile kt = key>>5, 8 KB/tile):
//  K: byte j at kt*8192 + (s>>1)*1024 + lane*16 + (s&1)*8  = K[kt*32+(lane&31)][s*16+(lane>>5)*8+j]
//  V: byte j at kt*8192 + fb*1024    + lane*16 + s2*8      = V[kt*32+s2*16+(lane>>5)*8+j][fb*32+(lane&31)]

__global__ __launch_bounds__(256) void gemm_qkv(
    const unsigned short* __restrict__ A,
    const unsigned short* __restrict__ Wt0, const unsigned short* __restrict__ Wt1, const unsigned short* __restrict__ Wt2,
    const float* __restrict__ b0, const float* __restrict__ b1, const float* __restrict__ b2,
    unsigned char* __restrict__ C0, unsigned char* __restrict__ C1, unsigned char* __restrict__ C2,
    int N)
{
    const unsigned short* Wt = (blockIdx.z == 0) ? Wt0 : (blockIdx.z == 1) ? Wt1 : Wt2;
    const float* bias        = (blockIdx.z == 0) ? b0  : (blockIdx.z == 1) ? b1  : b2;
    unsigned char* Cb        = (blockIdx.z == 0) ? C0  : (blockIdx.z == 1) ? C1  : C2;

    __shared__ __align__(16) unsigned short As[64][136];
    __shared__ __align__(16) unsigned short Bs[64][136];
    const int tid  = threadIdx.x;
    const int w    = tid >> 6;
    const int lane = tid & 63;
    const int quad = lane >> 4;
    const int l15  = lane & 15;
    const int m0 = blockIdx.x * 64;
    const int n0 = blockIdx.y * 64;

    floatx4 acc[4];
    #pragma unroll
    for (int t = 0; t < 4; ++t) acc[t] = (floatx4)0.0f;

    for (int kc = 0; kc < 256; kc += 128) {
        __syncthreads();
        #pragma unroll
        for (int idx = tid; idx < 1024; idx += 256) {
            int r = idx >> 4, g = idx & 15;
            *(short8*)&As[r][g * 8] = *(const short8*)&A[(size_t)(m0 + r) * 256 + kc + g * 8];
            *(short8*)&Bs[r][g * 8] = *(const short8*)&Wt[(size_t)(n0 + r) * 256 + kc + g * 8];
        }
        __syncthreads();
        #pragma unroll
        for (int s = 0; s < 4; ++s) {
            short8 a = *(const short8*)&As[w * 16 + l15][s * 32 + quad * 8];
            #pragma unroll
            for (int t = 0; t < 4; ++t) {
                short8 bfr = *(const short8*)&Bs[t * 16 + l15][s * 32 + quad * 8];
                acc[t] = MFMA16(a, bfr, acc[t]);
            }
        }
    }

    // ---- epilogue: acc -> fp8 LDS tile (64x80 overlay on As) -> layout-specific stores ----
    __syncthreads();
    unsigned char* T = (unsigned char*)&As[0][0];
    #pragma unroll
    for (int t = 0; t < 4; ++t) {
        int n = n0 + t * 16 + l15;
        float bs = bias[n];
        #pragma unroll
        for (int r = 0; r < 4; ++r)
            T[(w * 16 + quad * 4 + r) * 80 + t * 16 + l15] = f2fp8(acc[t][r] + bs);
    }
    __syncthreads();

    const int b  = m0 >> 12;             // batch (4096 keys each)
    const int mt = (m0 & 4095) >> 5;     // base 32-key tile within batch

    if (blockIdx.z == 0) {
        // Q row-major: 4 thr x 16B = full 64B row, coalesced dwordx4
        int row = tid >> 2, c16 = (tid & 3) * 16;
        int4 vq = *(const int4*)&T[row * 80 + c16];
        *(int4*)&Cb[(size_t)(m0 + row) * 256 + n0 + c16] = vq;
    } else {
        const int kt  = tid >> 7;          // 0..1 : 32-key tile within block
        const int sub = (tid >> 6) & 1;    // K: slice-pair | V: local f-block
        const int ln  = tid & 63;
        const int l31b = ln & 31, hib = ln >> 5;
        union { long h[2]; int4 v; unsigned char bts[16]; } o;
        if (blockIdx.z == 1) {
            #pragma unroll
            for (int h = 0; h < 2; ++h)
                o.h[h] = *(const long*)&T[(kt * 32 + l31b) * 80 + (sub * 2 + h) * 16 + hib * 8];
        } else {
            #pragma unroll
            for (int s2 = 0; s2 < 2; ++s2)
                #pragma unroll
                for (int j = 0; j < 8; ++j)
                    o.bts[s2 * 8 + j] = T[(kt * 32 + s2 * 16 + hib * 8 + j) * 80 + sub * 32 + l31b];
        }
        unsigned char* dst = Cb + (size_t)b * 1048576 + (size_t)(mt + kt) * 8192
                           + (size_t)((n0 >> 5) + sub) * 1024 + ln * 16;
        *(int4*)dst = o.v;
    }
}

// ---------------- flash attention v14: 2 independent blocks/CU (K staged, V streamed) ----------------
// Seven single-block-per-CU schedules all pinned MfmaUtil ~30%: one barrier domain/CU means
// every stall phase idles the whole CU. v14 halves the block (32 queries, 4 waves = 1 qg x
// 4 key-quarters, 256 thr) and shrinks LDS to 64 KB (double-buffered K only; V streamed from
// L2 via early-issued dwordx4 loads hidden under QK+softmax) -> grid 512 = 2 async blocks/CU.
// Same total MFMA work and wave count (8/CU), but two independent barrier domains co-schedule:
// one block's MFMA overlaps the other's stage/softmax/drain (m114). Reg budget: peak ~230 of
// 256 at 2 waves/SIMD -> no spill (v13 lesson: +48 regs spilled and cost 30%).

__global__ __launch_bounds__(256, 2) void flash_attn(
    const unsigned char* __restrict__ qg,      // fp8 Q row-major [b][n][256]
    const unsigned char* __restrict__ kp,      // fragment-packed fp8 K (slice-paired)
    const unsigned char* __restrict__ vp,      // fragment-packed fp8 V (slice-paired)
    const unsigned short* __restrict__ xb,     // bf16 x for residual
    const float* __restrict__ gamma,
    float* __restrict__ out)
{
    __shared__ __align__(16) unsigned char KVb[2][32768];  // [buf][kq quarter: K 8 KB x4]
    __shared__ float Ml[32];
    // merge overlay after the K-loop: Mb 32 x 264 f32 = 33,792 B (KV buffers dead by then)
    float* MbF = (float*)&KVb[0][0];

    const int tid  = threadIdx.x;       // 0..255
    const int w    = tid >> 6;          // wave = key quarter 0..3
    const int lane = tid & 63;
    const int l31  = lane & 31;
    const int hi   = lane >> 5;
    const int kq   = w;
    const int blk  = blockIdx.x;        // 0..511
    const int b    = (blk & 7) >> 1;               // XCD-pinned batch
    const int rt   = (blk >> 3) * 2 + (blk & 1);   // row-tile 0..127 (32 queries each)
    const int row0 = rt * 32;

    // Q fragments (B-operand of swapped QK: col = l&31 = query, k = hi*8+j), 8 B/lane
    const size_t baseQ = ((size_t)b * 4096 + row0 + l31) * 256 + hi * 8;
    long qf[16];
    #pragma unroll
    for (int s = 0; s < 16; ++s)
        qf[s] = *(const long*)&qg[baseQ + s * 16];

    const long ones8 = 0x3838383838383838L;    // e4m3 1.0 x8

    floatx16 ctx[8];
    #pragma unroll
    for (int i = 0; i < 8; ++i) ctx[i] = (floatx16)0.0f;
    floatx16 lacc = (floatx16)0.0f;

    const unsigned char* kb_b = kp + (size_t)b * 1048576;
    // this wave's V quarter (global, L2-resident): tile t at +t*8192, pair p at +p*1024
    const unsigned char* vq_b = vp + (size_t)b * 1048576 + (size_t)kq * 262144 + lane * 16;

    // stage K tile T -> BUF: 32 x 1KB chunks; wave w owns chunks c = p*4+w (p=0..7).
    // chunk map: c>>3 = key-quarter, (c&7)*1024 = offset within the quarter's 8 KB.
#define FA_STAGE(T, BUF)                                                             \
    {                                                                                \
        _Pragma("unroll")                                                            \
        for (int p = 0; p < 8; ++p) {                                                \
            const int c    = p * 4 + w;                                              \
            const int ckq  = c >> 3;                                                 \
            const int coff = (c & 7) * 1024;                                         \
            const unsigned char* src = kb_b                                          \
                + (size_t)ckq * 262144 + (size_t)(T) * 8192 + coff + lane * 16;      \
            GLOAD_LDS16(src, &KVb[BUF][ckq * 8192 + coff]);                          \
        }                                                                            \
    }

    FA_STAGE(0, 0)   // prologue

    for (int t = 0; t < 32; ++t) {
        const int buf = t & 1;
        __syncthreads();                 // drains vmcnt -> staging(t) complete & visible
        if (t < 31) FA_STAGE(t + 1, buf ^ 1)

        const unsigned char* kc = &KVb[buf][kq * 8192];
        const unsigned char* vt = vq_b + (size_t)t * 8192;

        // early V loads (half 0) -> hide L2 latency under QK
        longx2 v0[4];
        #pragma unroll
        for (int p = 0; p < 4; ++p) v0[p] = *(const longx2*)&vt[p * 1024];

        // ---- S^T = mfma(K, Q): D col = query (lane-local), rows = 32 keys ----
        longx2 kk[8];
        #pragma unroll
        for (int p = 0; p < 8; ++p)
            kk[p] = *(const longx2*)&kc[p * 1024 + lane * 16];
        floatx16 sa = (floatx16)0.0f, sb = (floatx16)0.0f;
        __builtin_amdgcn_s_setprio(1);
        #pragma unroll
        for (int p = 0; p < 8; ++p) {
            sa = MFMA32(kk[p].x, qf[2 * p],     sa);
            sb = MFMA32(kk[p].y, qf[2 * p + 1], sb);
        }
        __builtin_amdgcn_s_setprio(0);

        // V loads (half 1) -> hide under softmax VALU
        longx2 v1[4];
        #pragma unroll
        for (int p = 0; p < 4; ++p) v1[p] = *(const longx2*)&vt[(4 + p) * 1024];

        // ---- P = exp(S) -> fp8 in-register; permlane32_swap builds PV A-frags ----
        float e[16];
        #pragma unroll
        for (int r = 0; r < 16; ++r) e[r] = __expf(sa[r] + sb[r]);
        int X0 = __builtin_amdgcn_cvt_pk_fp8_f32(e[0],  e[1],  0,  false);
        X0     = __builtin_amdgcn_cvt_pk_fp8_f32(e[2],  e[3],  X0, true);
        int Y0 = __builtin_amdgcn_cvt_pk_fp8_f32(e[4],  e[5],  0,  false);
        Y0     = __builtin_amdgcn_cvt_pk_fp8_f32(e[6],  e[7],  Y0, true);
        int X1 = __builtin_amdgcn_cvt_pk_fp8_f32(e[8],  e[9],  0,  false);
        X1     = __builtin_amdgcn_cvt_pk_fp8_f32(e[10], e[11], X1, true);
        int Y1 = __builtin_amdgcn_cvt_pk_fp8_f32(e[12], e[13], 0,  false);
        Y1     = __builtin_amdgcn_cvt_pk_fp8_f32(e[14], e[15], Y1, true);
        asm volatile("v_permlane32_swap_b32 %0, %1" : "+v"(X0), "+v"(Y0));
        asm volatile("v_permlane32_swap_b32 %0, %1" : "+v"(X1), "+v"(Y1));
        union { int i2[2]; long l; } u0, u1;
        u0.i2[0] = X0; u0.i2[1] = Y0;
        u1.i2[0] = X1; u1.i2[1] = Y1;
        const long ap0 = u0.l;           // P[query = l&31][keys hi*8..+7 of slice 0]
        const long ap1 = u1.l;           // slice 1 (keys 16..31)

        // ---- row-sum via ones-MFMA + PV partials (V from registers) ----
        lacc = MFMA32(ap0, ones8, lacc);
        lacc = MFMA32(ap1, ones8, lacc);
        __builtin_amdgcn_s_setprio(1);
        #pragma unroll
        for (int p = 0; p < 4; ++p) {
            ctx[p] = MFMA32(ap0, v0[p].x, ctx[p]);
            ctx[p] = MFMA32(ap1, v0[p].y, ctx[p]);
        }
        #pragma unroll
        for (int p = 0; p < 4; ++p) {
            ctx[4 + p] = MFMA32(ap0, v1[p].x, ctx[4 + p]);
            ctx[4 + p] = MFMA32(ap1, v1[p].y, ctx[4 + p]);
        }
        __builtin_amdgcn_s_setprio(0);
    }
#undef FA_STAGE

    // ---- merge the 4 key-quarters (plain sums; maxless softmax is linear) ----
    __syncthreads();
    for (int pass = 3; pass >= 0; --pass) {
        if (kq == pass) {
            #pragma unroll
            for (int fb = 0; fb < 8; ++fb) {
                #pragma unroll
                for (int r = 0; r < 16; ++r) {
                    int row = (r & 3) + 8 * (r >> 2) + 4 * hi;
                    int idx = row * 264 + fb * 32 + l31;
                    float prev = (pass == 3) ? 0.0f : MbF[idx];
                    MbF[idx] = prev + ctx[fb][r];
                }
            }
            if (l31 == 0) {
                #pragma unroll
                for (int r = 0; r < 16; ++r) {
                    int row = (r & 3) + 8 * (r >> 2) + 4 * hi;
                    float prev = (pass == 3) ? 0.0f : Ml[row];
                    Ml[row] = prev + lacc[r];
                }
            }
        }
        __syncthreads();
    }

    // ---- cooperative epilogue: out = gamma * Mb / Ml + x (coalesced float4) ----
    const float g = gamma[0];
    const int row = tid >> 3;          // 0..31
    const int c0  = (tid & 7) * 32;    // 0..224
    const float rl = 1.0f / Ml[row];
    const size_t o = ((size_t)b * 4096 + rt * 32 + row) * 256 + c0;
    #pragma unroll
    for (int j = 0; j < 4; ++j) {
        short8 xv = *(const short8*)&xb[o + j * 8];
        float res[8];
        #pragma unroll
        for (int i = 0; i < 8; ++i)
            res[i] = g * MbF[row * 264 + c0 + j * 8 + i] * rl + bf2f((unsigned short)xv[i]);
        *(float4*)&out[o + j * 8]     = *(float4*)&res[0];
        *(float4*)&out[o + j * 8 + 4] = *(float4*)&res[4];
    }
}

// ---------------- host launch ----------------
// Workspace (~21 MB): 0 q8 4MB | 4M k8 4MB | 8M v8 4MB | 12M x_b bf16 8MB | 20M Wt_p/q/k/v 448KB
// 4 launches: prep_weights, gemm_bias, gemm_qkv (round-4 proven), flash_attn v14 (512 x 256).

extern "C" void kernel_launch(void* const* d_in, const int* in_sizes, int n_in,
                              void* d_out, int out_size, void* d_ws, size_t ws_size,
                              hipStream_t stream)
{
    const float* inp   = (const float*)d_in[0];
    const float* Wp    = (const float*)d_in[1];
    const float* bp    = (const float*)d_in[2];
    const float* Wq    = (const float*)d_in[3];
    const float* bq    = (const float*)d_in[4];
    const float* Wk    = (const float*)d_in[5];
    const float* bk    = (const float*)d_in[6];
    const float* Wv    = (const float*)d_in[7];
    const float* bv    = (const float*)d_in[8];
    const float* gamma = (const float*)d_in[9];
    float* out = (float*)d_out;

    char* ws = (char*)d_ws;
    unsigned char*  q8    = (unsigned char*)(ws + 0);
    unsigned char*  k8    = (unsigned char*)(ws + 4194304);
    unsigned char*  v8    = (unsigned char*)(ws + 8388608);
    unsigned short* x_b   = (unsigned short*)(ws + 12582912);
    unsigned short* Wt_p  = (unsigned short*)(ws + 20971520);
    unsigned short* Wt_q  = (unsigned short*)(ws + 21037056);
    unsigned short* Wt_k  = (unsigned short*)(ws + 21168128);
    unsigned short* Wt_v  = (unsigned short*)(ws + 21299200);

    prep_weights<<<896, 256, 0, stream>>>(Wp, Wq, Wk, Wv, Wt_p, Wt_q, Wt_k, Wt_v);
    gemm_bias<<<dim3(256, 4), 256, 0, stream>>>(inp, Wt_p, bp, x_b, 256);
    gemm_qkv<<<dim3(256, 4, 3), 256, 0, stream>>>(x_b, Wt_q, Wt_k, Wt_v, bq, bk, bv,
                                                  q8, k8, v8, 256);
    flash_attn<<<512, 256, 0, stream>>>(q8, k8, v8, x_b, gamma, out);
}

// Round 11
// 190.411 us; speedup vs baseline: 1.2544x; 1.2544x over previous
//
#include <hip/hip_runtime.h>
#include <hip/hip_bf16.h>
#include <stdint.h>

typedef __attribute__((ext_vector_type(8))) short short8;
typedef __attribute__((ext_vector_type(4))) float floatx4;
typedef __attribute__((ext_vector_type(16))) float floatx16;
typedef __attribute__((ext_vector_type(2))) long longx2;

#define DEVI __device__ __forceinline__
#define MFMA16(a, b, c) __builtin_amdgcn_mfma_f32_16x16x32_bf16((a), (b), (c), 0, 0, 0)
#define MFMA32(a, b, c) __builtin_amdgcn_mfma_f32_32x32x16_fp8_fp8((a), (b), (c), 0, 0, 0)

typedef __attribute__((address_space(3))) unsigned int lds_u32;
typedef __attribute__((address_space(1))) const unsigned int glb_u32;
// async 16B/lane DMA global->LDS: lds dest = wave-uniform base + lane*16 (contiguous 1KB/wave)
#define GLOAD_LDS16(g, l) __builtin_amdgcn_global_load_lds((glb_u32*)(g), (lds_u32*)(l), 16, 0, 0)

DEVI unsigned short f2bf(float x) {
    union { float f; unsigned int u; } v; v.f = x;
    unsigned int r = v.u + 0x7FFFu + ((v.u >> 16) & 1u);
    return (unsigned short)(r >> 16);
}
DEVI float bf2f(unsigned short h) {
    union { unsigned int u; float f; } v; v.u = ((unsigned int)h) << 16;
    return v.f;
}
DEVI unsigned char f2fp8(float x) {   // OCP e4m3 via HW converter
    int c = __builtin_amdgcn_cvt_pk_fp8_f32(x, x, 0, false);
    return (unsigned char)(c & 0xFF);
}

// ---------------- fused weight prep: all 4 transpose+casts in one launch ----------------
// Tp[n][k] = bf16(Wp[k][n]) (128x256 -> 256x128); Tq/Tk/Tv same for 256x256.
__global__ __launch_bounds__(256) void prep_weights(
    const float* __restrict__ Wp, const float* __restrict__ Wq,
    const float* __restrict__ Wk, const float* __restrict__ Wv,
    unsigned short* __restrict__ Tp, unsigned short* __restrict__ Tq,
    unsigned short* __restrict__ Tk, unsigned short* __restrict__ Tv)
{
    int idx = blockIdx.x * blockDim.x + threadIdx.x;   // 0 .. 229375
    if (idx < 32768) {
        int k = idx >> 8, n = idx & 255;
        Tp[n * 128 + k] = f2bf(Wp[idx]);
    } else {
        int r = idx - 32768;
        int m = r >> 16, i = r & 65535;                // m = 0,1,2
        const float* W   = (m == 0) ? Wq : (m == 1) ? Wk : Wv;
        unsigned short* T = (m == 0) ? Tq : (m == 1) ? Tk : Tv;
        int k = i >> 8, n = i & 255;
        T[n * 256 + k] = f2bf(W[i]);
    }
}

// ---------------- projection GEMM: x = f32_in @ Wp^T + bias (fused cast, bf16 out) ----------------

__global__ __launch_bounds__(256) void gemm_bias(
    const float* __restrict__ A,               // f32 input [16384][128]
    const unsigned short* __restrict__ Wt,     // bf16 [256][128]
    const float* __restrict__ bias,
    unsigned short* __restrict__ Cb,           // bf16 out [16384][256]
    int N)
{
    __shared__ __align__(16) unsigned short As[64][136];
    __shared__ __align__(16) unsigned short Bs[64][136];
    const int tid  = threadIdx.x;
    const int w    = tid >> 6;
    const int lane = tid & 63;
    const int quad = lane >> 4;
    const int l15  = lane & 15;
    const int m0 = blockIdx.x * 64;
    const int n0 = blockIdx.y * 64;

    floatx4 acc[4];
    #pragma unroll
    for (int t = 0; t < 4; ++t) acc[t] = (floatx4)0.0f;

    // K = 128: single chunk. A staged f32 -> bf16 in-register (fused cast).
    #pragma unroll
    for (int it = 0; it < 8; ++it) {
        int idx = tid + it * 256;             // 0..2047 float4s
        int r = idx >> 5, c4 = idx & 31;
        float4 v = *(const float4*)&A[(size_t)(m0 + r) * 128 + c4 * 4];
        ushort4 o;
        o.x = f2bf(v.x); o.y = f2bf(v.y); o.z = f2bf(v.z); o.w = f2bf(v.w);
        *(ushort4*)&As[r][c4 * 4] = o;
    }
    #pragma unroll
    for (int it = 0; it < 4; ++it) {
        int idx = tid + it * 256;             // 0..1023 x 8 bf16
        int r = idx >> 4, g = idx & 15;
        *(short8*)&Bs[r][g * 8] = *(const short8*)&Wt[(size_t)(n0 + r) * 128 + g * 8];
    }
    __syncthreads();
    #pragma unroll
    for (int s = 0; s < 4; ++s) {
        short8 a = *(const short8*)&As[w * 16 + l15][s * 32 + quad * 8];
        #pragma unroll
        for (int t = 0; t < 4; ++t) {
            short8 bfr = *(const short8*)&Bs[t * 16 + l15][s * 32 + quad * 8];
            acc[t] = MFMA16(a, bfr, acc[t]);
        }
    }

    // epilogue via LDS overlay -> coalesced 16B stores (BOTH column halves: 512 int4s, 256 thr)
    __syncthreads();
    unsigned short* T = &As[0][0];            // 64 x 80 ushort overlay (10 KB)
    #pragma unroll
    for (int t = 0; t < 4; ++t) {
        int n = n0 + t * 16 + l15;
        float bs = bias[n];
        #pragma unroll
        for (int r = 0; r < 4; ++r)
            T[(w * 16 + quad * 4 + r) * 80 + t * 16 + l15] = f2bf(acc[t][r] + bs);
    }
    __syncthreads();
    int row = tid >> 2, c8 = (tid & 3) * 8;
    #pragma unroll
    for (int half = 0; half < 2; ++half) {
        int4 ov = *(const int4*)&T[row * 80 + c8 + half * 32];
        *(int4*)&Cb[(size_t)(m0 + row) * N + n0 + c8 + half * 32] = ov;
    }
}

// ---------------- fused Q/K/V GEMM with fp8 + fragment-packed output ----------------
// blockIdx.z selects weight/bias/output. Q written row-major fp8; K and V written DIRECTLY
// in the 32x32x16 slice-paired fragment layout flash_attn consumes. All global stores
// 16B/thread via a 5 KB LDS tile-transpose overlaid on As.
//
// Packed layouts (per batch, 1 MB, tile kt = key>>5, 8 KB/tile):
//  K: byte j at kt*8192 + (s>>1)*1024 + lane*16 + (s&1)*8  = K[kt*32+(lane&31)][s*16+(lane>>5)*8+j]
//  V: byte j at kt*8192 + fb*1024    + lane*16 + s2*8      = V[kt*32+s2*16+(lane>>5)*8+j][fb*32+(lane&31)]

__global__ __launch_bounds__(256) void gemm_qkv(
    const unsigned short* __restrict__ A,
    const unsigned short* __restrict__ Wt0, const unsigned short* __restrict__ Wt1, const unsigned short* __restrict__ Wt2,
    const float* __restrict__ b0, const float* __restrict__ b1, const float* __restrict__ b2,
    unsigned char* __restrict__ C0, unsigned char* __restrict__ C1, unsigned char* __restrict__ C2,
    int N)
{
    const unsigned short* Wt = (blockIdx.z == 0) ? Wt0 : (blockIdx.z == 1) ? Wt1 : Wt2;
    const float* bias        = (blockIdx.z == 0) ? b0  : (blockIdx.z == 1) ? b1  : b2;
    unsigned char* Cb        = (blockIdx.z == 0) ? C0  : (blockIdx.z == 1) ? C1  : C2;

    __shared__ __align__(16) unsigned short As[64][136];
    __shared__ __align__(16) unsigned short Bs[64][136];
    const int tid  = threadIdx.x;
    const int w    = tid >> 6;
    const int lane = tid & 63;
    const int quad = lane >> 4;
    const int l15  = lane & 15;
    const int m0 = blockIdx.x * 64;
    const int n0 = blockIdx.y * 64;

    floatx4 acc[4];
    #pragma unroll
    for (int t = 0; t < 4; ++t) acc[t] = (floatx4)0.0f;

    for (int kc = 0; kc < 256; kc += 128) {
        __syncthreads();
        #pragma unroll
        for (int idx = tid; idx < 1024; idx += 256) {
            int r = idx >> 4, g = idx & 15;
            *(short8*)&As[r][g * 8] = *(const short8*)&A[(size_t)(m0 + r) * 256 + kc + g * 8];
            *(short8*)&Bs[r][g * 8] = *(const short8*)&Wt[(size_t)(n0 + r) * 256 + kc + g * 8];
        }
        __syncthreads();
        #pragma unroll
        for (int s = 0; s < 4; ++s) {
            short8 a = *(const short8*)&As[w * 16 + l15][s * 32 + quad * 8];
            #pragma unroll
            for (int t = 0; t < 4; ++t) {
                short8 bfr = *(const short8*)&Bs[t * 16 + l15][s * 32 + quad * 8];
                acc[t] = MFMA16(a, bfr, acc[t]);
            }
        }
    }

    // ---- epilogue: acc -> fp8 LDS tile (64x80 overlay on As) -> layout-specific stores ----
    __syncthreads();
    unsigned char* T = (unsigned char*)&As[0][0];
    #pragma unroll
    for (int t = 0; t < 4; ++t) {
        int n = n0 + t * 16 + l15;
        float bs = bias[n];
        #pragma unroll
        for (int r = 0; r < 4; ++r)
            T[(w * 16 + quad * 4 + r) * 80 + t * 16 + l15] = f2fp8(acc[t][r] + bs);
    }
    __syncthreads();

    const int b  = m0 >> 12;             // batch (4096 keys each)
    const int mt = (m0 & 4095) >> 5;     // base 32-key tile within batch

    if (blockIdx.z == 0) {
        // Q row-major: 4 thr x 16B = full 64B row, coalesced dwordx4
        int row = tid >> 2, c16 = (tid & 3) * 16;
        int4 vq = *(const int4*)&T[row * 80 + c16];
        *(int4*)&Cb[(size_t)(m0 + row) * 256 + n0 + c16] = vq;
    } else {
        const int kt  = tid >> 7;          // 0..1 : 32-key tile within block
        const int sub = (tid >> 6) & 1;    // K: slice-pair | V: local f-block
        const int ln  = tid & 63;
        const int l31b = ln & 31, hib = ln >> 5;
        union { long h[2]; int4 v; unsigned char bts[16]; } o;
        if (blockIdx.z == 1) {
            #pragma unroll
            for (int h = 0; h < 2; ++h)
                o.h[h] = *(const long*)&T[(kt * 32 + l31b) * 80 + (sub * 2 + h) * 16 + hib * 8];
        } else {
            #pragma unroll
            for (int s2 = 0; s2 < 2; ++s2)
                #pragma unroll
                for (int j = 0; j < 8; ++j)
                    o.bts[s2 * 8 + j] = T[(kt * 32 + s2 * 16 + hib * 8 + j) * 80 + sub * 32 + l31b];
        }
        unsigned char* dst = Cb + (size_t)b * 1048576 + (size_t)(mt + kt) * 8192
                           + (size_t)((n0 >> 5) + sub) * 1024 + ln * 16;
        *(int4*)dst = o.v;
    }
}

// ---------------- flash attention v11 (best measured: 93.8 us @ MfmaUtil 31%) ----------------
// LDS DMA double-buffer pipeline; slice-paired ds_read_b128 fragments; in-register softmax
// (cvt_pk_fp8 + permlane32_swap); setprio around MFMA clusters. global_load_lds stages the
// next 32-key tile (64 KB, all 4 quarters) into buf^1 while compute consumes buf; one
// barrier/iter drains DMAs issued a full iteration earlier. 512 thr = (2 query-groups x
// 4 key-quarters); grid 256 = 1 block/CU. Structural plateau for this decomposition:
// 8 non-spilling schedule variants (v8-v14) all land 94-108 us at ~30% MfmaUtil; occupancy
// is LDS+register bound (ctx alone = 128 regs/wave), so the serial QK->softmax->PV chain
// per wave sets the floor.

__global__ __launch_bounds__(512, 2) void flash_attn(
    const unsigned char* __restrict__ qg,      // fp8 Q row-major [b][n][256]
    const unsigned char* __restrict__ kp,      // fragment-packed fp8 K (slice-paired)
    const unsigned char* __restrict__ vp,      // fragment-packed fp8 V (slice-paired)
    const unsigned short* __restrict__ xb,     // bf16 x for residual
    const float* __restrict__ gamma,
    float* __restrict__ out)
{
    __shared__ __align__(16) unsigned char KV[2][65536]; // [buf][kq: K 8K, V 8K]
    // merge overlay after the K-loop: Mb 64 x 264 f32 (67,584 B) + Ml 64 f32 (<= 131,072)
    float* MbF = (float*)&KV[0][0];
    float* Ml  = MbF + 64 * 264;

    const int tid  = threadIdx.x;
    const int w    = tid >> 6;
    const int lane = tid & 63;
    const int l31  = lane & 31;
    const int hi   = lane >> 5;
    const int kq   = w & 3;         // key quarter 0..3
    const int rw   = w >> 2;        // query group 0..1
    const int blk  = blockIdx.x;
    const int b    = (blk & 7) >> 1;              // XCD-pinned batch
    const int rt   = (blk >> 3) * 2 + (blk & 1);  // row-tile 0..63 (64 queries each)
    const int row0 = rt * 64 + rw * 32;

    // Q fragments (B-operand of swapped QK: col = l&31 = query, k = hi*8+j), 8 B/lane
    const size_t baseQ = ((size_t)b * 4096 + row0 + l31) * 256 + hi * 8;
    long qf[16];
    #pragma unroll
    for (int s = 0; s < 16; ++s)
        qf[s] = *(const long*)&qg[baseQ + s * 16];

    const long ones8 = 0x3838383838383838L;    // e4m3 1.0 x8

    floatx16 ctx[8];
    #pragma unroll
    for (int i = 0; i < 8; ++i) ctx[i] = (floatx16)0.0f;
    floatx16 lacc = (floatx16)0.0f;

    const unsigned char* kb_b = kp + (size_t)b * 1048576;
    const unsigned char* vb_b = vp + (size_t)b * 1048576;

    // stage(t -> buf): 64 KB = 64 x 1KB chunks; wave w DMAs chunks c = p*8+w.
    // chunk map: c>>4 = key-quarter, (c>>3)&1 = K/V, (c&7)*1024 = offset in the 8 KB half.
#define FA_STAGE(T, BUF)                                                             \
    {                                                                                \
        _Pragma("unroll")                                                            \
        for (int p = 0; p < 8; ++p) {                                                \
            const int c    = p * 8 + w;                                              \
            const int ckq  = c >> 4;                                                 \
            const int csel = (c >> 3) & 1;                                           \
            const int coff = (c & 7) * 1024;                                         \
            const unsigned char* src = (csel ? vb_b : kb_b)                          \
                + (size_t)ckq * 262144 + (size_t)(T) * 8192 + coff + lane * 16;      \
            GLOAD_LDS16(src, &KV[BUF][ckq * 16384 + csel * 8192 + coff]);            \
        }                                                                            \
    }

    FA_STAGE(0, 0)   // prologue

    for (int t = 0; t < 32; ++t) {
        const int buf = t & 1;
        __syncthreads();                 // drains vmcnt -> staging(t) complete & visible
        if (t < 31) FA_STAGE(t + 1, buf ^ 1)

        const unsigned char* kc = &KV[buf][kq * 16384];
        const unsigned char* vc = &KV[buf][kq * 16384 + 8192];

        // ---- S^T = mfma(K, Q): D col = query (lane-local), rows = 32 keys ----
        longx2 kk[8];
        #pragma unroll
        for (int p = 0; p < 8; ++p)
            kk[p] = *(const longx2*)&kc[p * 1024 + lane * 16];
        floatx16 sa = (floatx16)0.0f, sb = (floatx16)0.0f;
        __builtin_amdgcn_s_setprio(1);
        #pragma unroll
        for (int p = 0; p < 8; ++p) {
            sa = MFMA32(kk[p].x, qf[2 * p],     sa);
            sb = MFMA32(kk[p].y, qf[2 * p + 1], sb);
        }
        __builtin_amdgcn_s_setprio(0);

        // ---- P = exp(S) -> fp8 in-register; permlane32_swap builds PV A-frags ----
        float e[16];
        #pragma unroll
        for (int r = 0; r < 16; ++r) e[r] = __expf(sa[r] + sb[r]);
        int X0 = __builtin_amdgcn_cvt_pk_fp8_f32(e[0],  e[1],  0,  false);
        X0     = __builtin_amdgcn_cvt_pk_fp8_f32(e[2],  e[3],  X0, true);
        int Y0 = __builtin_amdgcn_cvt_pk_fp8_f32(e[4],  e[5],  0,  false);
        Y0     = __builtin_amdgcn_cvt_pk_fp8_f32(e[6],  e[7],  Y0, true);
        int X1 = __builtin_amdgcn_cvt_pk_fp8_f32(e[8],  e[9],  0,  false);
        X1     = __builtin_amdgcn_cvt_pk_fp8_f32(e[10], e[11], X1, true);
        int Y1 = __builtin_amdgcn_cvt_pk_fp8_f32(e[12], e[13], 0,  false);
        Y1     = __builtin_amdgcn_cvt_pk_fp8_f32(e[14], e[15], Y1, true);
        asm volatile("v_permlane32_swap_b32 %0, %1" : "+v"(X0), "+v"(Y0));
        asm volatile("v_permlane32_swap_b32 %0, %1" : "+v"(X1), "+v"(Y1));
        union { int i2[2]; long l; } u0, u1;
        u0.i2[0] = X0; u0.i2[1] = Y0;
        u1.i2[0] = X1; u1.i2[1] = Y1;
        const long ap0 = u0.l;           // P[query = l&31][keys hi*8..+7 of slice 0]
        const long ap1 = u1.l;           // slice 1 (keys 16..31)

        // ---- row-sum via ones-MFMA + PV partials (V pairs via ds_read_b128) ----
        lacc = MFMA32(ap0, ones8, lacc);
        lacc = MFMA32(ap1, ones8, lacc);
        __builtin_amdgcn_s_setprio(1);
        #pragma unroll
        for (int p = 0; p < 8; ++p) {
            longx2 vv = *(const longx2*)&vc[p * 1024 + lane * 16];
            ctx[p] = MFMA32(ap0, vv.x, ctx[p]);
            ctx[p] = MFMA32(ap1, vv.y, ctx[p]);
        }
        __builtin_amdgcn_s_setprio(0);
    }
#undef FA_STAGE

    // ---- merge the 4 key-quarters (plain sums; maxless softmax is linear) ----
    __syncthreads();
    for (int pass = 3; pass >= 0; --pass) {
        if (kq == pass) {
            #pragma unroll
            for (int fb = 0; fb < 8; ++fb) {
                #pragma unroll
                for (int r = 0; r < 16; ++r) {
                    int row = rw * 32 + (r & 3) + 8 * (r >> 2) + 4 * hi;
                    int idx = row * 264 + fb * 32 + l31;
                    float prev = (pass == 3) ? 0.0f : MbF[idx];
                    MbF[idx] = prev + ctx[fb][r];
                }
            }
            if (l31 == 0) {
                #pragma unroll
                for (int r = 0; r < 16; ++r) {
                    int row = rw * 32 + (r & 3) + 8 * (r >> 2) + 4 * hi;
                    float prev = (pass == 3) ? 0.0f : Ml[row];
                    Ml[row] = prev + lacc[r];
                }
            }
        }
        __syncthreads();
    }

    // ---- cooperative epilogue: out = gamma * Mb / Ml + x (coalesced float4) ----
    const float g = gamma[0];
    const int row = tid >> 3;          // 0..63
    const int c0  = (tid & 7) * 32;    // 0..224
    const float rl = 1.0f / Ml[row];
    const size_t o = ((size_t)b * 4096 + rt * 64 + row) * 256 + c0;
    #pragma unroll
    for (int j = 0; j < 4; ++j) {
        short8 xv = *(const short8*)&xb[o + j * 8];
        float res[8];
        #pragma unroll
        for (int i = 0; i < 8; ++i)
            res[i] = g * MbF[row * 264 + c0 + j * 8 + i] * rl + bf2f((unsigned short)xv[i]);
        *(float4*)&out[o + j * 8]     = *(float4*)&res[0];
        *(float4*)&out[o + j * 8 + 4] = *(float4*)&res[4];
    }
}

// ---------------- host launch ----------------
// Workspace (~21 MB): 0 q8 4MB | 4M k8 4MB | 8M v8 4MB | 12M x_b bf16 8MB | 20M Wt_p/q/k/v 448KB
// 4 launches (round-4 proven best, 190.4 us): prep_weights, gemm_bias, gemm_qkv, flash_attn.

extern "C" void kernel_launch(void* const* d_in, const int* in_sizes, int n_in,
                              void* d_out, int out_size, void* d_ws, size_t ws_size,
                              hipStream_t stream)
{
    const float* inp   = (const float*)d_in[0];
    const float* Wp    = (const float*)d_in[1];
    const float* bp    = (const float*)d_in[2];
    const float* Wq    = (const float*)d_in[3];
    const float* bq    = (const float*)d_in[4];
    const float* Wk    = (const float*)d_in[5];
    const float* bk    = (const float*)d_in[6];
    const float* Wv    = (const float*)d_in[7];
    const float* bv    = (const float*)d_in[8];
    const float* gamma = (const float*)d_in[9];
    float* out = (float*)d_out;

    char* ws = (char*)d_ws;
    unsigned char*  q8    = (unsigned char*)(ws + 0);
    unsigned char*  k8    = (unsigned char*)(ws + 4194304);
    unsigned char*  v8    = (unsigned char*)(ws + 8388608);
    unsigned short* x_b   = (unsigned short*)(ws + 12582912);
    unsigned short* Wt_p  = (unsigned short*)(ws + 20971520);
    unsigned short* Wt_q  = (unsigned short*)(ws + 21037056);
    unsigned short* Wt_k  = (unsigned short*)(ws + 21168128);
    unsigned short* Wt_v  = (unsigned short*)(ws + 21299200);

    prep_weights<<<896, 256, 0, stream>>>(Wp, Wq, Wk, Wv, Wt_p, Wt_q, Wt_k, Wt_v);
    gemm_bias<<<dim3(256, 4), 256, 0, stream>>>(inp, Wt_p, bp, x_b, 256);
    gemm_qkv<<<dim3(256, 4, 3), 256, 0, stream>>>(x_b, Wt_q, Wt_k, Wt_v, bq, bk, bv,
                                                  q8, k8, v8, 256);
    flash_attn<<<256, 512, 0, stream>>>(q8, k8, v8, x_b, gamma, out);
}

// Round 12
// 187.638 us; speedup vs baseline: 1.2729x; 1.0148x over previous
//
#include <hip/hip_runtime.h>
#include <hip/hip_bf16.h>
#include <stdint.h>

typedef __attribute__((ext_vector_type(8))) short short8;
typedef __attribute__((ext_vector_type(4))) float floatx4;
typedef __attribute__((ext_vector_type(16))) float floatx16;
typedef __attribute__((ext_vector_type(2))) long longx2;

#define DEVI __device__ __forceinline__
#define MFMA16(a, b, c) __builtin_amdgcn_mfma_f32_16x16x32_bf16((a), (b), (c), 0, 0, 0)
#define MFMA32(a, b, c) __builtin_amdgcn_mfma_f32_32x32x16_fp8_fp8((a), (b), (c), 0, 0, 0)

typedef __attribute__((address_space(3))) unsigned int lds_u32;
typedef __attribute__((address_space(1))) const unsigned int glb_u32;
// async 16B/lane DMA global->LDS: lds dest = wave-uniform base + lane*16 (contiguous 1KB/wave)
#define GLOAD_LDS16(g, l) __builtin_amdgcn_global_load_lds((glb_u32*)(g), (lds_u32*)(l), 16, 0, 0)

DEVI unsigned short f2bf(float x) {
    union { float f; unsigned int u; } v; v.f = x;
    unsigned int r = v.u + 0x7FFFu + ((v.u >> 16) & 1u);
    return (unsigned short)(r >> 16);
}
DEVI float bf2f(unsigned short h) {
    union { unsigned int u; float f; } v; v.u = ((unsigned int)h) << 16;
    return v.f;
}
DEVI unsigned char f2fp8(float x) {   // OCP e4m3 via HW converter
    int c = __builtin_amdgcn_cvt_pk_fp8_f32(x, x, 0, false);
    return (unsigned char)(c & 0xFF);
}

// ---------------- weight prep v2: 64x64 LDS tile-transpose, coalesced both sides ----------------
// Old version wrote 2-byte scatters at stride 256B (~32x write amplification). Now: coalesced
// float4 reads -> LDS transpose -> coalesced short8 writes. 56 blocks: 8 for Wp (128x256),
// 16 each for Wq/Wk/Wv (256x256). All inputs have row stride 256.
__global__ __launch_bounds__(256) void prep_weights(
    const float* __restrict__ Wp, const float* __restrict__ Wq,
    const float* __restrict__ Wk, const float* __restrict__ Wv,
    unsigned short* __restrict__ Tp, unsigned short* __restrict__ Tq,
    unsigned short* __restrict__ Tk, unsigned short* __restrict__ Tv)
{
    __shared__ unsigned short Tl[64][72];
    const int bb = blockIdx.x;
    const float* W; unsigned short* T; int K; int tt;
    if (bb < 8)       { W = Wp; T = Tp; K = 128; tt = bb;      }
    else if (bb < 24) { W = Wq; T = Tq; K = 256; tt = bb - 8;  }
    else if (bb < 40) { W = Wk; T = Tk; K = 256; tt = bb - 24; }
    else              { W = Wv; T = Tv; K = 256; tt = bb - 40; }
    const int r0 = (tt >> 2) * 64;   // k-range base (Wp: 0..1, others 0..3)
    const int c0 = (tt & 3) * 64;    // n-range base
    const int tid = threadIdx.x;

    #pragma unroll
    for (int i = 0; i < 4; ++i) {
        int u = tid + i * 256;               // 0..1023: r = u>>4, c4 = u&15
        int r = u >> 4, c4 = u & 15;
        float4 v = *(const float4*)&W[(size_t)(r0 + r) * 256 + c0 + c4 * 4];
        Tl[c4 * 4 + 0][r] = f2bf(v.x);
        Tl[c4 * 4 + 1][r] = f2bf(v.y);
        Tl[c4 * 4 + 2][r] = f2bf(v.z);
        Tl[c4 * 4 + 3][r] = f2bf(v.w);
    }
    __syncthreads();
    #pragma unroll
    for (int i = 0; i < 2; ++i) {
        int u = tid + i * 256;               // 0..511: orow = u>>3, g = u&7
        int orow = u >> 3, g = u & 7;
        *(short8*)&T[(size_t)(c0 + orow) * K + r0 + g * 8] = *(const short8*)&Tl[orow][g * 8];
    }
}

// ---------------- projection GEMM: x = f32_in @ Wp^T + bias (fused cast, bf16 out) ----------------

__global__ __launch_bounds__(256) void gemm_bias(
    const float* __restrict__ A,               // f32 input [16384][128]
    const unsigned short* __restrict__ Wt,     // bf16 [256][128]
    const float* __restrict__ bias,
    unsigned short* __restrict__ Cb,           // bf16 out [16384][256]
    int N)
{
    __shared__ __align__(16) unsigned short As[64][136];
    __shared__ __align__(16) unsigned short Bs[64][136];
    const int tid  = threadIdx.x;
    const int w    = tid >> 6;
    const int lane = tid & 63;
    const int quad = lane >> 4;
    const int l15  = lane & 15;
    const int m0 = blockIdx.x * 64;
    const int n0 = blockIdx.y * 64;

    floatx4 acc[4];
    #pragma unroll
    for (int t = 0; t < 4; ++t) acc[t] = (floatx4)0.0f;

    // K = 128: single chunk. A staged f32 -> bf16 in-register (fused cast).
    #pragma unroll
    for (int it = 0; it < 8; ++it) {
        int idx = tid + it * 256;             // 0..2047 float4s
        int r = idx >> 5, c4 = idx & 31;
        float4 v = *(const float4*)&A[(size_t)(m0 + r) * 128 + c4 * 4];
        ushort4 o;
        o.x = f2bf(v.x); o.y = f2bf(v.y); o.z = f2bf(v.z); o.w = f2bf(v.w);
        *(ushort4*)&As[r][c4 * 4] = o;
    }
    #pragma unroll
    for (int it = 0; it < 4; ++it) {
        int idx = tid + it * 256;             // 0..1023 x 8 bf16
        int r = idx >> 4, g = idx & 15;
        *(short8*)&Bs[r][g * 8] = *(const short8*)&Wt[(size_t)(n0 + r) * 128 + g * 8];
    }
    __syncthreads();
    #pragma unroll
    for (int s = 0; s < 4; ++s) {
        short8 a = *(const short8*)&As[w * 16 + l15][s * 32 + quad * 8];
        #pragma unroll
        for (int t = 0; t < 4; ++t) {
            short8 bfr = *(const short8*)&Bs[t * 16 + l15][s * 32 + quad * 8];
            acc[t] = MFMA16(a, bfr, acc[t]);
        }
    }

    // epilogue via LDS overlay -> coalesced 16B stores (BOTH column halves: 512 int4s, 256 thr)
    __syncthreads();
    unsigned short* T = &As[0][0];            // 64 x 80 ushort overlay (10 KB)
    #pragma unroll
    for (int t = 0; t < 4; ++t) {
        int n = n0 + t * 16 + l15;
        float bs = bias[n];
        #pragma unroll
        for (int r = 0; r < 4; ++r)
            T[(w * 16 + quad * 4 + r) * 80 + t * 16 + l15] = f2bf(acc[t][r] + bs);
    }
    __syncthreads();
    int row = tid >> 2, c8 = (tid & 3) * 8;
    #pragma unroll
    for (int half = 0; half < 2; ++half) {
        int4 ov = *(const int4*)&T[row * 80 + c8 + half * 32];
        *(int4*)&Cb[(size_t)(m0 + row) * N + n0 + c8 + half * 32] = ov;
    }
}

// ---------------- fused Q/K/V GEMM v2: full-N blocks (A staged once, 4x fewer A reads) ----------------
// blockIdx.z selects weight/bias/output; blockIdx.x = 64-row m-tile. A (64x256 bf16, 33.8 KB)
// staged ONCE per block; the 4 n-tiles loop stages only the 32 KB weight tile each. Epilogue
// per n-tile is the round-4-verified fp8 fragment-pack (n0 = nt*64). LDS 72.7 KB -> 2 blocks/CU.
//
// Packed layouts (per batch, 1 MB, tile kt = key>>5, 8 KB/tile):
//  K: byte j at kt*8192 + (s>>1)*1024 + lane*16 + (s&1)*8  = K[kt*32+(lane&31)][s*16+(lane>>5)*8+j]
//  V: byte j at kt*8192 + fb*1024    + lane*16 + s2*8      = V[kt*32+s2*16+(lane>>5)*8+j][fb*32+(lane&31)]

__global__ __launch_bounds__(256) void gemm_qkv(
    const unsigned short* __restrict__ A,
    const unsigned short* __restrict__ Wt0, const unsigned short* __restrict__ Wt1, const unsigned short* __restrict__ Wt2,
    const float* __restrict__ b0, const float* __restrict__ b1, const float* __restrict__ b2,
    unsigned char* __restrict__ C0, unsigned char* __restrict__ C1, unsigned char* __restrict__ C2,
    int N)
{
    const unsigned short* Wt = (blockIdx.z == 0) ? Wt0 : (blockIdx.z == 1) ? Wt1 : Wt2;
    const float* bias        = (blockIdx.z == 0) ? b0  : (blockIdx.z == 1) ? b1  : b2;
    unsigned char* Cb        = (blockIdx.z == 0) ? C0  : (blockIdx.z == 1) ? C1  : C2;

    __shared__ __align__(16) unsigned short As[64][264];
    __shared__ __align__(16) unsigned short Bs[64][264];
    __shared__ __align__(16) unsigned char  Tt[64 * 80];
    const int tid  = threadIdx.x;
    const int w    = tid >> 6;
    const int lane = tid & 63;
    const int quad = lane >> 4;
    const int l15  = lane & 15;
    const int m0 = blockIdx.x * 64;

    // stage A full-K once (64 x 256 bf16)
    #pragma unroll
    for (int it = 0; it < 8; ++it) {
        int u = tid + it * 256;              // 0..2047: r = u>>5, g = u&31
        int r = u >> 5, g = u & 31;
        *(short8*)&As[r][g * 8] = *(const short8*)&A[(size_t)(m0 + r) * 256 + g * 8];
    }

    const int b  = m0 >> 12;             // batch (4096 keys each)
    const int mt = (m0 & 4095) >> 5;     // base 32-key tile within batch

    for (int nt = 0; nt < 4; ++nt) {
        __syncthreads();                 // A visible (first iter); prior Bs-MFMA + Tt-store readers done
        #pragma unroll
        for (int it = 0; it < 8; ++it) {
            int u = tid + it * 256;
            int r = u >> 5, g = u & 31;
            *(short8*)&Bs[r][g * 8] = *(const short8*)&Wt[(size_t)(nt * 64 + r) * 256 + g * 8];
        }
        __syncthreads();

        floatx4 acc[4];
        #pragma unroll
        for (int t = 0; t < 4; ++t) acc[t] = (floatx4)0.0f;
        #pragma unroll
        for (int s = 0; s < 8; ++s) {
            short8 a = *(const short8*)&As[w * 16 + l15][s * 32 + quad * 8];
            #pragma unroll
            for (int t = 0; t < 4; ++t) {
                short8 bfr = *(const short8*)&Bs[t * 16 + l15][s * 32 + quad * 8];
                acc[t] = MFMA16(a, bfr, acc[t]);
            }
        }

        // ---- epilogue: acc -> fp8 Tt tile -> layout-specific stores (n0 = nt*64) ----
        const int n0 = nt * 64;
        #pragma unroll
        for (int t = 0; t < 4; ++t) {
            int n = n0 + t * 16 + l15;
            float bs = bias[n];
            #pragma unroll
            for (int r = 0; r < 4; ++r)
                Tt[(w * 16 + quad * 4 + r) * 80 + t * 16 + l15] = f2fp8(acc[t][r] + bs);
        }
        __syncthreads();

        if (blockIdx.z == 0) {
            // Q row-major: 4 thr x 16B = full 64B row chunk, coalesced dwordx4
            int row = tid >> 2, c16 = (tid & 3) * 16;
            int4 vq = *(const int4*)&Tt[row * 80 + c16];
            *(int4*)&Cb[(size_t)(m0 + row) * 256 + n0 + c16] = vq;
        } else {
            const int kt  = tid >> 7;          // 0..1 : 32-key tile within block
            const int sub = (tid >> 6) & 1;    // K: slice-pair | V: local f-block
            const int ln  = tid & 63;
            const int l31b = ln & 31, hib = ln >> 5;
            union { long h[2]; int4 v; unsigned char bts[16]; } o;
            if (blockIdx.z == 1) {
                #pragma unroll
                for (int h = 0; h < 2; ++h)
                    o.h[h] = *(const long*)&Tt[(kt * 32 + l31b) * 80 + (sub * 2 + h) * 16 + hib * 8];
            } else {
                #pragma unroll
                for (int s2 = 0; s2 < 2; ++s2)
                    #pragma unroll
                    for (int j = 0; j < 8; ++j)
                        o.bts[s2 * 8 + j] = Tt[(kt * 32 + s2 * 16 + hib * 8 + j) * 80 + sub * 32 + l31b];
            }
            unsigned char* dst = Cb + (size_t)b * 1048576 + (size_t)(mt + kt) * 8192
                               + (size_t)((n0 >> 5) + sub) * 1024 + ln * 16;
            *(int4*)dst = o.v;
        }
    }
}

// ---------------- flash attention v11 (best measured: 93.5 us @ MfmaUtil 31%) ----------------
// LDS DMA double-buffer pipeline; slice-paired ds_read_b128 fragments; in-register softmax
// (cvt_pk_fp8 + permlane32_swap); setprio around MFMA clusters. global_load_lds stages the
// next 32-key tile (64 KB, all 4 quarters) into buf^1 while compute consumes buf; one
// barrier/iter drains DMAs issued a full iteration earlier. 512 thr = (2 query-groups x
// 4 key-quarters); grid 256 = 1 block/CU. Structural plateau for this decomposition:
// 8 non-spilling schedule variants (v8-v14) all land 94-108 us at ~30% MfmaUtil.

__global__ __launch_bounds__(512, 2) void flash_attn(
    const unsigned char* __restrict__ qg,      // fp8 Q row-major [b][n][256]
    const unsigned char* __restrict__ kp,      // fragment-packed fp8 K (slice-paired)
    const unsigned char* __restrict__ vp,      // fragment-packed fp8 V (slice-paired)
    const unsigned short* __restrict__ xb,     // bf16 x for residual
    const float* __restrict__ gamma,
    float* __restrict__ out)
{
    __shared__ __align__(16) unsigned char KV[2][65536]; // [buf][kq: K 8K, V 8K]
    // merge overlay after the K-loop: Mb 64 x 264 f32 (67,584 B) + Ml 64 f32 (<= 131,072)
    float* MbF = (float*)&KV[0][0];
    float* Ml  = MbF + 64 * 264;

    const int tid  = threadIdx.x;
    const int w    = tid >> 6;
    const int lane = tid & 63;
    const int l31  = lane & 31;
    const int hi   = lane >> 5;
    const int kq   = w & 3;         // key quarter 0..3
    const int rw   = w >> 2;        // query group 0..1
    const int blk  = blockIdx.x;
    const int b    = (blk & 7) >> 1;              // XCD-pinned batch
    const int rt   = (blk >> 3) * 2 + (blk & 1);  // row-tile 0..63 (64 queries each)
    const int row0 = rt * 64 + rw * 32;

    // Q fragments (B-operand of swapped QK: col = l&31 = query, k = hi*8+j), 8 B/lane
    const size_t baseQ = ((size_t)b * 4096 + row0 + l31) * 256 + hi * 8;
    long qf[16];
    #pragma unroll
    for (int s = 0; s < 16; ++s)
        qf[s] = *(const long*)&qg[baseQ + s * 16];

    const long ones8 = 0x3838383838383838L;    // e4m3 1.0 x8

    floatx16 ctx[8];
    #pragma unroll
    for (int i = 0; i < 8; ++i) ctx[i] = (floatx16)0.0f;
    floatx16 lacc = (floatx16)0.0f;

    const unsigned char* kb_b = kp + (size_t)b * 1048576;
    const unsigned char* vb_b = vp + (size_t)b * 1048576;

    // stage(t -> buf): 64 KB = 64 x 1KB chunks; wave w DMAs chunks c = p*8+w.
    // chunk map: c>>4 = key-quarter, (c>>3)&1 = K/V, (c&7)*1024 = offset in the 8 KB half.
#define FA_STAGE(T, BUF)                                                             \
    {                                                                                \
        _Pragma("unroll")                                                            \
        for (int p = 0; p < 8; ++p) {                                                \
            const int c    = p * 8 + w;                                              \
            const int ckq  = c >> 4;                                                 \
            const int csel = (c >> 3) & 1;                                           \
            const int coff = (c & 7) * 1024;                                         \
            const unsigned char* src = (csel ? vb_b : kb_b)                          \
                + (size_t)ckq * 262144 + (size_t)(T) * 8192 + coff + lane * 16;      \
            GLOAD_LDS16(src, &KV[BUF][ckq * 16384 + csel * 8192 + coff]);            \
        }                                                                            \
    }

    FA_STAGE(0, 0)   // prologue

    for (int t = 0; t < 32; ++t) {
        const int buf = t & 1;
        __syncthreads();                 // drains vmcnt -> staging(t) complete & visible
        if (t < 31) FA_STAGE(t + 1, buf ^ 1)

        const unsigned char* kc = &KV[buf][kq * 16384];
        const unsigned char* vc = &KV[buf][kq * 16384 + 8192];

        // ---- S^T = mfma(K, Q): D col = query (lane-local), rows = 32 keys ----
        longx2 kk[8];
        #pragma unroll
        for (int p = 0; p < 8; ++p)
            kk[p] = *(const longx2*)&kc[p * 1024 + lane * 16];
        floatx16 sa = (floatx16)0.0f, sb = (floatx16)0.0f;
        __builtin_amdgcn_s_setprio(1);
        #pragma unroll
        for (int p = 0; p < 8; ++p) {
            sa = MFMA32(kk[p].x, qf[2 * p],     sa);
            sb = MFMA32(kk[p].y, qf[2 * p + 1], sb);
        }
        __builtin_amdgcn_s_setprio(0);

        // ---- P = exp(S) -> fp8 in-register; permlane32_swap builds PV A-frags ----
        float e[16];
        #pragma unroll
        for (int r = 0; r < 16; ++r) e[r] = __expf(sa[r] + sb[r]);
        int X0 = __builtin_amdgcn_cvt_pk_fp8_f32(e[0],  e[1],  0,  false);
        X0     = __builtin_amdgcn_cvt_pk_fp8_f32(e[2],  e[3],  X0, true);
        int Y0 = __builtin_amdgcn_cvt_pk_fp8_f32(e[4],  e[5],  0,  false);
        Y0     = __builtin_amdgcn_cvt_pk_fp8_f32(e[6],  e[7],  Y0, true);
        int X1 = __builtin_amdgcn_cvt_pk_fp8_f32(e[8],  e[9],  0,  false);
        X1     = __builtin_amdgcn_cvt_pk_fp8_f32(e[10], e[11], X1, true);
        int Y1 = __builtin_amdgcn_cvt_pk_fp8_f32(e[12], e[13], 0,  false);
        Y1     = __builtin_amdgcn_cvt_pk_fp8_f32(e[14], e[15], Y1, true);
        asm volatile("v_permlane32_swap_b32 %0, %1" : "+v"(X0), "+v"(Y0));
        asm volatile("v_permlane32_swap_b32 %0, %1" : "+v"(X1), "+v"(Y1));
        union { int i2[2]; long l; } u0, u1;
        u0.i2[0] = X0; u0.i2[1] = Y0;
        u1.i2[0] = X1; u1.i2[1] = Y1;
        const long ap0 = u0.l;           // P[query = l&31][keys hi*8..+7 of slice 0]
        const long ap1 = u1.l;           // slice 1 (keys 16..31)

        // ---- row-sum via ones-MFMA + PV partials (V pairs via ds_read_b128) ----
        lacc = MFMA32(ap0, ones8, lacc);
        lacc = MFMA32(ap1, ones8, lacc);
        __builtin_amdgcn_s_setprio(1);
        #pragma unroll
        for (int p = 0; p < 8; ++p) {
            longx2 vv = *(const longx2*)&vc[p * 1024 + lane * 16];
            ctx[p] = MFMA32(ap0, vv.x, ctx[p]);
            ctx[p] = MFMA32(ap1, vv.y, ctx[p]);
        }
        __builtin_amdgcn_s_setprio(0);
    }
#undef FA_STAGE

    // ---- merge the 4 key-quarters (plain sums; maxless softmax is linear) ----
    __syncthreads();
    for (int pass = 3; pass >= 0; --pass) {
        if (kq == pass) {
            #pragma unroll
            for (int fb = 0; fb < 8; ++fb) {
                #pragma unroll
                for (int r = 0; r < 16; ++r) {
                    int row = rw * 32 + (r & 3) + 8 * (r >> 2) + 4 * hi;
                    int idx = row * 264 + fb * 32 + l31;
                    float prev = (pass == 3) ? 0.0f : MbF[idx];
                    MbF[idx] = prev + ctx[fb][r];
                }
            }
            if (l31 == 0) {
                #pragma unroll
                for (int r = 0; r < 16; ++r) {
                    int row = rw * 32 + (r & 3) + 8 * (r >> 2) + 4 * hi;
                    float prev = (pass == 3) ? 0.0f : Ml[row];
                    Ml[row] = prev + lacc[r];
                }
            }
        }
        __syncthreads();
    }

    // ---- cooperative epilogue: out = gamma * Mb / Ml + x (coalesced float4) ----
    const float g = gamma[0];
    const int row = tid >> 3;          // 0..63
    const int c0  = (tid & 7) * 32;    // 0..224
    const float rl = 1.0f / Ml[row];
    const size_t o = ((size_t)b * 4096 + rt * 64 + row) * 256 + c0;
    #pragma unroll
    for (int j = 0; j < 4; ++j) {
        short8 xv = *(const short8*)&xb[o + j * 8];
        float res[8];
        #pragma unroll
        for (int i = 0; i < 8; ++i)
            res[i] = g * MbF[row * 264 + c0 + j * 8 + i] * rl + bf2f((unsigned short)xv[i]);
        *(float4*)&out[o + j * 8]     = *(float4*)&res[0];
        *(float4*)&out[o + j * 8 + 4] = *(float4*)&res[4];
    }
}

// ---------------- host launch ----------------
// Workspace (~21 MB): 0 q8 4MB | 4M k8 4MB | 8M v8 4MB | 12M x_b bf16 8MB | 20M Wt_p/q/k/v 448KB
// 4 launches: prep_weights v2 (tiled transpose), gemm_bias, gemm_qkv v2 (full-N), flash_attn v11.

extern "C" void kernel_launch(void* const* d_in, const int* in_sizes, int n_in,
                              void* d_out, int out_size, void* d_ws, size_t ws_size,
                              hipStream_t stream)
{
    const float* inp   = (const float*)d_in[0];
    const float* Wp    = (const float*)d_in[1];
    const float* bp    = (const float*)d_in[2];
    const float* Wq    = (const float*)d_in[3];
    const float* bq    = (const float*)d_in[4];
    const float* Wk    = (const float*)d_in[5];
    const float* bk    = (const float*)d_in[6];
    const float* Wv    = (const float*)d_in[7];
    const float* bv    = (const float*)d_in[8];
    const float* gamma = (const float*)d_in[9];
    float* out = (float*)d_out;

    char* ws = (char*)d_ws;
    unsigned char*  q8    = (unsigned char*)(ws + 0);
    unsigned char*  k8    = (unsigned char*)(ws + 4194304);
    unsigned char*  v8    = (unsigned char*)(ws + 8388608);
    unsigned short* x_b   = (unsigned short*)(ws + 12582912);
    unsigned short* Wt_p  = (unsigned short*)(ws + 20971520);
    unsigned short* Wt_q  = (unsigned short*)(ws + 21037056);
    unsigned short* Wt_k  = (unsigned short*)(ws + 21168128);
    unsigned short* Wt_v  = (unsigned short*)(ws + 21299200);

    prep_weights<<<56, 256, 0, stream>>>(Wp, Wq, Wk, Wv, Wt_p, Wt_q, Wt_k, Wt_v);
    gemm_bias<<<dim3(256, 4), 256, 0, stream>>>(inp, Wt_p, bp, x_b, 256);
    gemm_qkv<<<dim3(256, 1, 3), 256, 0, stream>>>(x_b, Wt_q, Wt_k, Wt_v, bq, bk, bv,
                                                  q8, k8, v8, 256);
    flash_attn<<<256, 512, 0, stream>>>(q8, k8, v8, x_b, gamma, out);
}